// Round 6
// baseline (466.874 us; speedup 1.0000x reference)
//
#include <hip/hip_runtime.h>

#define NN 10000      // nodes
#define NE 320000     // edges (before self-loops)
#define NB 64         // graphs
#define CIN 128       // in_channels
#define CEC 64        // edge_channels
#define CHID 256      // hidden
#define CMLP 512
#define CNC 4
#define K1 (2 * CIN + CEC)    // 320
#define K23 (2 * CHID + CEC)  // 576

static __host__ int cdiv(int a, int b) { return (a + b - 1) / b; }

typedef short sfrag __attribute__((ext_vector_type(8)));   // 8 bf16 in 4 VGPRs
typedef float f4 __attribute__((ext_vector_type(4)));

static __device__ __forceinline__ ushort f2b(float f) {
  union { float f; unsigned u; } v; v.f = f;
  unsigned r = (v.u + 0x7fffu + ((v.u >> 16) & 1u)) >> 16;
  return (ushort)r;
}
static __device__ __forceinline__ float b2f(ushort u) {
  union { unsigned u; float f; } v; v.u = ((unsigned)u) << 16;
  return v.f;
}

// ---------------- setup kernels ----------------

// zero ptr/pooled/counts/stats; ea32 = 1.0 (PyG self-loop edge_attr fill)
__global__ __launch_bounds__(256) void k_init(int* __restrict__ ptr, float* __restrict__ pooled,
                                              float* __restrict__ counts, float* __restrict__ stats,
                                              float* __restrict__ ea32) {
  int i = blockIdx.x * 256 + threadIdx.x;
  if (i <= NN) ptr[i] = 0;
  if (i < NB * CHID) pooled[i] = 0.f;
  if (i < NB) counts[i] = 0.f;
  if (i < 6 * CHID) stats[i] = 0.f;
  if (i < NN * CEC) ea32[i] = 1.0f;
}

// direct edge_attr scatter: ea32[dst] += eattr[e]  (wave per edge, 8 edges/wave)
__global__ __launch_bounds__(256) void k_scatter(const float* __restrict__ eattr, const int* __restrict__ ei,
                                                 float* __restrict__ ea32) {
  int base = blockIdx.x * 32 + ((threadIdx.x >> 6) << 3);  // NE/32 = 10000 blocks
  int lane = threadIdx.x & 63;
#pragma unroll
  for (int j = 0; j < 8; ++j) {
    int e = base + j;
    int dst = ei[NE + e];
    float v = eattr[(size_t)e * CEC + lane];
    atomicAdd(&ea32[(size_t)dst * CEC + lane], v);
  }
}

// blocks [0,1250): edge-degree histogram; blocks [1250,1290): batch histogram -> counts
__global__ __launch_bounds__(256) void k_count(const int* __restrict__ ei, int* __restrict__ ptr,
                                               const int* __restrict__ batch, float* __restrict__ counts) {
  int b = blockIdx.x;
  if (b < 1250) {
    int e = b * 256 + threadIdx.x;  // 1250*256 == NE exactly
    atomicAdd(&ptr[ei[NE + e] + 1], 1);
  } else {
    __shared__ int hist[NB];
    if (threadIdx.x < NB) hist[threadIdx.x] = 0;
    __syncthreads();
    int n = (b - 1250) * 256 + threadIdx.x;
    if (n < NN) atomicAdd(&hist[batch[n]], 1);
    __syncthreads();
    if (threadIdx.x < NB && hist[threadIdx.x]) atomicAdd(&counts[threadIdx.x], (float)hist[threadIdx.x]);
  }
}

// single-block inclusive scan over ptr[0..NN] + fused pos/degf writeout
__global__ __launch_bounds__(1024) void k_scan(int* __restrict__ ptr, int* __restrict__ pos,
                                               float* __restrict__ degf) {
  __shared__ int wsum[16];
  __shared__ int chtot;
  int carry = 0;
  const int n1 = NN + 1;
  const int lane = threadIdx.x & 63;
  const int wid = threadIdx.x >> 6;
  for (int base = 0; base < n1; base += 1024) {
    int i = base + threadIdx.x;
    int v = (i < n1) ? ptr[i] : 0;
    int sc = v;
#pragma unroll
    for (int d = 1; d < 64; d <<= 1) {
      int t = __shfl_up(sc, d);
      if (lane >= d) sc += t;
    }
    if (lane == 63) wsum[wid] = sc;
    __syncthreads();
    if (wid == 0 && lane < 16) {
      int ws = wsum[lane];
      int s2 = ws;
#pragma unroll
      for (int d = 1; d < 16; d <<= 1) {
        int t = __shfl_up(s2, d);
        if (lane >= d) s2 += t;
      }
      wsum[lane] = s2 - ws;  // exclusive
      if (lane == 15) chtot = s2;
    }
    __syncthreads();
    if (i < n1) ptr[i] = sc + wsum[wid] + carry;
    carry += chtot;
    __syncthreads();
  }
  for (int i = threadIdx.x; i < NN; i += 1024) {
    int p = ptr[i], q = ptr[i + 1];
    pos[i] = p;
    degf[i] = (float)(q - p + 1);  // +1 self-loop
  }
}

// counting-sort placement: srcs in CSR order
__global__ __launch_bounds__(256) void k_fill(const int* __restrict__ ei, int* __restrict__ pos,
                                              int* __restrict__ srcs) {
  int e = blockIdx.x * 256 + threadIdx.x;  // 1250*256 == NE
  int d = ei[NE + e];
  int idx = atomicAdd(&pos[d], 1);
  srcs[idx] = ei[e];
}

// A1[:, 0:128] = bf16(degf * x); xb = bf16(x)
__global__ __launch_bounds__(256) void k_prep(const float4* __restrict__ x, const float* __restrict__ degf,
                                              ushort* __restrict__ A1, ushort* __restrict__ xb) {
  int gid = blockIdx.x * 256 + threadIdx.x;  // NN*32 = 320000 = 1250*256
  int node = gid >> 5;
  int c4 = (gid & 31) << 2;
  float d = degf[node];
  float4 v = x[gid];
  ushort4 o = { f2b(d * v.x), f2b(d * v.y), f2b(d * v.z), f2b(d * v.w) };
  *(ushort4*)&A1[(size_t)node * K1 + c4] = o;
  ushort4 xo = { f2b(v.x), f2b(v.y), f2b(v.z), f2b(v.w) };
  *(ushort4*)&xb[(size_t)node * CIN + c4] = xo;
}

// fused: ea32 -> bf16 panels + layer-1 gather of x. Wave per node.
__global__ __launch_bounds__(256) void k_eag(const float* __restrict__ ea32, const ushort* __restrict__ xb,
                                             const int* __restrict__ ptr, const int* __restrict__ srcs,
                                             ushort* __restrict__ A1, ushort* __restrict__ A23) {
  int node = blockIdx.x * 4 + (threadIdx.x >> 6);
  int lane = threadIdx.x & 63;
  int s = ptr[node], e = ptr[node + 1];

  ushort eb = f2b(ea32[(size_t)node * CEC + lane]);
  A1[(size_t)node * K1 + 2 * CIN + lane] = eb;
  A23[(size_t)node * K23 + 2 * CHID + lane] = eb;

  // layer-1 gather: G = x_i + sum x_src (bf16 table, shfl-broadcast indices)
  ushort2 own = *(const ushort2*)&xb[(size_t)node * CIN + lane * 2];
  float gx = b2f(own.x), gy = b2f(own.y);
  for (int k0 = s; k0 < e; k0 += 16) {
    int rem = e - k0;
    int myi = (lane < 16 && lane < rem) ? srcs[k0 + lane] : 0;
    if (rem >= 16) {
#pragma unroll
      for (int j = 0; j < 16; ++j) {
        int idx = __shfl(myi, j);
        ushort2 v = *(const ushort2*)&xb[(size_t)idx * CIN + lane * 2];
        gx += b2f(v.x); gy += b2f(v.y);
      }
    } else {
#pragma unroll
      for (int j = 0; j < 16; ++j) {
        int idx = __shfl(myi, j);
        ushort2 v = *(const ushort2*)&xb[(size_t)idx * CIN + lane * 2];
        if (j < rem) { gx += b2f(v.x); gy += b2f(v.y); }
      }
    }
  }
  ushort2 go = { f2b(gx), f2b(gy) };
  *(ushort2*)&A1[(size_t)node * K1 + CIN + lane * 2] = go;
}

// layers 2/3 gather, both 128-channel slices in one launch (blocks [0,2500)=slice0, [2500,5000)=slice1)
__global__ __launch_bounds__(256) void k_gather256(const ushort* __restrict__ hb, const int* __restrict__ ptr,
                                                   const int* __restrict__ srcs, ushort* __restrict__ A23) {
  int bx = blockIdx.x;
  int half = bx >= (NN / 4);
  int node = (bx - half * (NN / 4)) * 4 + (threadIdx.x >> 6);
  int coff = half << 7;
  int lane = threadIdx.x & 63;
  const ushort* hbl = hb + coff + lane * 2;
  ushort2 own = *(const ushort2*)&hbl[(size_t)node * CHID];
  float ax = b2f(own.x), ay = b2f(own.y);
  int s = ptr[node], e = ptr[node + 1];
  for (int k0 = s; k0 < e; k0 += 16) {
    int rem = e - k0;
    int myi = (lane < 16 && lane < rem) ? srcs[k0 + lane] : 0;
    if (rem >= 16) {
#pragma unroll
      for (int j = 0; j < 16; ++j) {
        int idx = __shfl(myi, j);
        ushort2 v = *(const ushort2*)&hbl[(size_t)idx * CHID];
        ax += b2f(v.x); ay += b2f(v.y);
      }
    } else {
#pragma unroll
      for (int j = 0; j < 16; ++j) {
        int idx = __shfl(myi, j);
        ushort2 v = *(const ushort2*)&hbl[(size_t)idx * CHID];
        if (j < rem) { ax += b2f(v.x); ay += b2f(v.y); }
      }
    }
  }
  ushort2 o = { f2b(ax), f2b(ay) };
  *(ushort2*)&A23[(size_t)node * K23 + CHID + coff + lane * 2] = o;
}

// all three weight transposes in one launch: flat over 256*(K1+2*K23) = 376832 = 1472*256
__global__ __launch_bounds__(256) void k_wt3(const float* __restrict__ W1, const float* __restrict__ W2,
                                             const float* __restrict__ W3, ushort* __restrict__ Wt1,
                                             ushort* __restrict__ Wt2, ushort* __restrict__ Wt3) {
  int i = blockIdx.x * 256 + threadIdx.x;
  const float* W; ushort* Wt; int Ktot; int j = i;
  if (j < 256 * K1) { W = W1; Wt = Wt1; Ktot = K1; }
  else {
    j -= 256 * K1;
    if (j < 256 * K23) { W = W2; Wt = Wt2; Ktot = K23; }
    else { j -= 256 * K23; W = W3; Wt = Wt3; Ktot = K23; }
  }
  int n = j / Ktot;
  int k = j - n * Ktot;
  Wt[j] = f2b(W[(size_t)k * CHID + n]);
}

// ---------------- MFMA GEMM 64x64 tile, register-prefetch dbuf + fused bias/relu/BN-stats ----------------
__global__ __launch_bounds__(256) void k_gemm(const ushort* __restrict__ Ag, const ushort* __restrict__ Wt,
                                              const float* __restrict__ bias, const float* __restrict__ degf,
                                              float* __restrict__ out, float* __restrict__ colsum,
                                              float* __restrict__ colsq, int Ktot) {
  __shared__ ushort As[64 * 40];  // 64 rows x 32 k, stride 40 (16B-aligned, 2-way alias free)
  __shared__ ushort Bs[64 * 40];
  const int bm = blockIdx.x * 64;
  const int bn = blockIdx.y * 64;
  const int tid = threadIdx.x;
  const int w = tid >> 6;
  const int lane = tid & 63;
  const int ln = lane & 15;
  const int quad = lane >> 4;

  f4 acc[4];
#pragma unroll
  for (int nf = 0; nf < 4; ++nf) acc[nf] = (f4){0.f, 0.f, 0.f, 0.f};

  const int rA = tid >> 2;         // 0..63
  const int kq = (tid & 3) << 3;   // 0,8,16,24
  const int rowAc = min(bm + rA, NN - 1);  // clamp; garbage rows never stored
  const ushort* ap = Ag + (size_t)rowAc * Ktot + kq;
  const ushort* bp = Wt + (size_t)(bn + rA) * Ktot + kq;

  const int iters = Ktot >> 5;
  uint4 av = *(const uint4*)ap;
  uint4 bv = *(const uint4*)bp;
  for (int it = 0; it < iters; ++it) {
    *(uint4*)&As[rA * 40 + kq] = av;
    *(uint4*)&Bs[rA * 40 + kq] = bv;
    __syncthreads();
    if (it + 1 < iters) {  // prefetch next K-tile while MFMAs run
      av = *(const uint4*)(ap + (it + 1) * 32);
      bv = *(const uint4*)(bp + (it + 1) * 32);
    }
    sfrag a = *(const sfrag*)&As[(w * 16 + ln) * 40 + quad * 8];
#pragma unroll
    for (int nf = 0; nf < 4; ++nf) {
      sfrag b = *(const sfrag*)&Bs[(nf * 16 + ln) * 40 + quad * 8];
      acc[nf] = __builtin_amdgcn_mfma_f32_16x16x32_bf16(a, b, acc[nf], 0, 0, 0);
    }
    __syncthreads();
  }

  float bcol[4];
#pragma unroll
  for (int nf = 0; nf < 4; ++nf) bcol[nf] = bias[bn + nf * 16 + ln];
  float ssum[4] = {0.f, 0.f, 0.f, 0.f}, sqq[4] = {0.f, 0.f, 0.f, 0.f};
  int rbase = bm + w * 16 + quad * 4;
#pragma unroll
  for (int r = 0; r < 4; ++r) {
    int row = rbase + r;
    bool valid = row < NN;
    float d = valid ? degf[row] : 0.f;
#pragma unroll
    for (int nf = 0; nf < 4; ++nf) {
      float v = fmaxf(acc[nf][r] + d * bcol[nf], 0.f);
      if (valid) {
        out[(size_t)row * CHID + bn + nf * 16 + ln] = v;
        ssum[nf] += v;
        sqq[nf] += v * v;
      }
    }
  }
#pragma unroll
  for (int nf = 0; nf < 4; ++nf) {
    float s = ssum[nf], q = sqq[nf];
    s += __shfl_xor(s, 16); s += __shfl_xor(s, 32);
    q += __shfl_xor(q, 16); q += __shfl_xor(q, 32);
    if (quad == 0) {
      atomicAdd(&colsum[bn + nf * 16 + ln], s);
      atomicAdd(&colsq[bn + nf * 16 + ln], q);
    }
  }
}

// ---------------- BN apply (layers 1,2): inline bnfin; writes hb + next A-panel only ----------------
__global__ __launch_bounds__(256) void k_bnapply(const float4* __restrict__ t, const float* __restrict__ colsum,
                                                 const float* __restrict__ colsq, const float* __restrict__ g,
                                                 const float* __restrict__ be, ushort* __restrict__ Apanel,
                                                 ushort* __restrict__ hb, const float* __restrict__ degf) {
  int gid = blockIdx.x * 256 + threadIdx.x;  // NN*64
  int node = gid >> 6;
  int c4 = (gid & 63) << 2;
  float sc[4], sh[4];
#pragma unroll
  for (int j = 0; j < 4; ++j) {
    int c = c4 + j;
    float mu = colsum[c] * (1.f / (float)NN);
    float var = colsq[c] * (1.f / (float)NN) - mu * mu;
    float inv = rsqrtf(var + 1e-5f);
    sc[j] = g[c] * inv;
    sh[j] = be[c] - mu * sc[j];
  }
  float4 v = t[gid];
  float o0 = fmaxf(fmaf(v.x, sc[0], sh[0]), 0.f);
  float o1 = fmaxf(fmaf(v.y, sc[1], sh[1]), 0.f);
  float o2 = fmaxf(fmaf(v.z, sc[2], sh[2]), 0.f);
  float o3 = fmaxf(fmaf(v.w, sc[3], sh[3]), 0.f);
  ushort4 ho = { f2b(o0), f2b(o1), f2b(o2), f2b(o3) };
  *(ushort4*)&hb[(size_t)node * CHID + c4] = ho;
  float d = degf[node];
  ushort4 ao = { f2b(d * o0), f2b(d * o1), f2b(d * o2), f2b(d * o3) };
  *(ushort4*)&Apanel[(size_t)node * K23 + c4] = ao;
}

// ---------------- layer-3 BN + relu + segment pool, fused ----------------
__global__ __launch_bounds__(256) void k_poolbn(const float* __restrict__ t, const float* __restrict__ colsum,
                                                const float* __restrict__ colsq, const float* __restrict__ g,
                                                const float* __restrict__ be, const int* __restrict__ batch,
                                                float* __restrict__ pooled) {
  __shared__ int bsh[64];
  int r0 = blockIdx.x * 64;
  int c = threadIdx.x;
  int rows = min(64, NN - r0);
  if (c < rows) bsh[c] = batch[r0 + c];
  __syncthreads();
  float mu = colsum[c] * (1.f / (float)NN);
  float var = colsq[c] * (1.f / (float)NN) - mu * mu;
  float inv = rsqrtf(var + 1e-5f);
  float sc = g[c] * inv;
  float sh = be[c] - mu * sc;
  float acc = 0.f;
  int cur = bsh[0];
  for (int r = 0; r < rows; ++r) {
    int gg = bsh[r];
    if (gg != cur) {
      atomicAdd(&pooled[cur * CHID + c], acc);
      acc = 0.f;
      cur = gg;
    }
    acc += fmaxf(fmaf(t[(size_t)(r0 + r) * CHID + c], sc, sh), 0.f);
  }
  atomicAdd(&pooled[cur * CHID + c], acc);
}

// ---------------- MLP head (split: fc1 over 256 blocks, fc2 tiny) ----------------
__global__ __launch_bounds__(128) void k_fc1(const float* __restrict__ pooled, const float* __restrict__ counts,
                                             const float* __restrict__ nb, const float* __restrict__ w1,
                                             const float* __restrict__ b1, float* __restrict__ z) {
  int g = blockIdx.x >> 2;
  int o = ((blockIdx.x & 3) << 7) + threadIdx.x;
  __shared__ float zin[CHID + 1 + CIN];  // 385
  for (int i = threadIdx.x; i < CHID + 1 + CIN; i += 128) {
    zin[i] = (i < CHID) ? pooled[g * CHID + i]
           : (i == CHID) ? counts[g] * 0.025f  // / MAX_SIZE(40)
           : nb[g * CIN + (i - CHID - 1)];
  }
  __syncthreads();
  float acc = b1[o];
  for (int k = 0; k < CHID + 1 + CIN; ++k) acc = fmaf(zin[k], w1[k * CMLP + o], acc);
  z[g * CMLP + o] = fmaxf(acc, 0.f);
}

__global__ __launch_bounds__(64) void k_fc2(const float* __restrict__ z, const float* __restrict__ w2,
                                            const float* __restrict__ b2, float* __restrict__ out) {
  int g = blockIdx.x;
  int l = threadIdx.x;
  float p0 = 0.f, p1 = 0.f, p2 = 0.f, p3 = 0.f;
  for (int k = l; k < CMLP; k += 64) {
    float zv = z[g * CMLP + k];
    p0 = fmaf(zv, w2[k * CNC + 0], p0);
    p1 = fmaf(zv, w2[k * CNC + 1], p1);
    p2 = fmaf(zv, w2[k * CNC + 2], p2);
    p3 = fmaf(zv, w2[k * CNC + 3], p3);
  }
#pragma unroll
  for (int d = 1; d < 64; d <<= 1) {
    p0 += __shfl_xor(p0, d); p1 += __shfl_xor(p1, d);
    p2 += __shfl_xor(p2, d); p3 += __shfl_xor(p3, d);
  }
  if (l == 0) {
    out[g * CNC + 0] = p0 + b2[0];
    out[g * CNC + 1] = p1 + b2[1];
    out[g * CNC + 2] = p2 + b2[2];
    out[g * CNC + 3] = p3 + b2[3];
  }
}

// ---------------- launch ----------------

extern "C" void kernel_launch(void* const* d_in, const int* in_sizes, int n_in,
                              void* d_out, int out_size, void* d_ws, size_t ws_size,
                              hipStream_t stream) {
  const float* x     = (const float*)d_in[0];
  const int*   ei    = (const int*)d_in[1];
  const float* eattr = (const float*)d_in[2];
  const int*   batch = (const int*)d_in[3];
  const float* nbr   = (const float*)d_in[4];
  const float* W1 = (const float*)d_in[5];
  const float* b1 = (const float*)d_in[6];
  const float* g1 = (const float*)d_in[7];
  const float* be1 = (const float*)d_in[8];
  const float* W2 = (const float*)d_in[9];
  const float* b2 = (const float*)d_in[10];
  const float* g2 = (const float*)d_in[11];
  const float* be2 = (const float*)d_in[12];
  const float* W3 = (const float*)d_in[13];
  const float* b3 = (const float*)d_in[14];
  const float* g3 = (const float*)d_in[15];
  const float* be3 = (const float*)d_in[16];
  const float* fc1w = (const float*)d_in[17];
  const float* fc1b = (const float*)d_in[18];
  const float* fc2w = (const float*)d_in[19];
  const float* fc2b = (const float*)d_in[20];
  float* out = (float*)d_out;

  char* ws = (char*)d_ws;
  size_t off = 0;
  auto alloc = [&](size_t bytes) {
    void* p = ws + off;
    off = (off + bytes + 255) & ~(size_t)255;
    return p;
  };
  int*    ptr    = (int*)alloc((NN + 1) * sizeof(int));
  int*    pos    = (int*)alloc(NN * sizeof(int));
  float*  degf   = (float*)alloc(NN * sizeof(float));
  int*    srcs   = (int*)alloc(NE * sizeof(int));
  float*  ea32   = (float*)alloc((size_t)NN * CEC * sizeof(float));  // 2.56 MB, L2-resident
  ushort* A1     = (ushort*)alloc((size_t)NN * K1 * sizeof(ushort));
  ushort* A23    = (ushort*)alloc((size_t)NN * K23 * sizeof(ushort));
  ushort* Wt1    = (ushort*)alloc((size_t)256 * K1 * sizeof(ushort));
  ushort* Wt2    = (ushort*)alloc((size_t)256 * K23 * sizeof(ushort));
  ushort* Wt3    = (ushort*)alloc((size_t)256 * K23 * sizeof(ushort));
  ushort* xb     = (ushort*)alloc((size_t)NN * CIN * sizeof(ushort));
  ushort* hb     = (ushort*)alloc((size_t)NN * CHID * sizeof(ushort));
  float*  tmp    = (float*)alloc((size_t)NN * CHID * sizeof(float));
  float*  stats  = (float*)alloc(6 * CHID * sizeof(float));  // [layer][sum|sq][256]
  float*  pooled = (float*)alloc((size_t)NB * CHID * sizeof(float));
  float*  counts = (float*)alloc(NB * sizeof(float));
  float*  zmlp   = (float*)alloc((size_t)NB * CMLP * sizeof(float));
  (void)ws_size; (void)n_in; (void)in_sizes; (void)out_size;

  float* cs1 = stats + 0 * 512, *cq1 = stats + 0 * 512 + 256;
  float* cs2 = stats + 1 * 512, *cq2 = stats + 1 * 512 + 256;
  float* cs3 = stats + 2 * 512, *cq3 = stats + 2 * 512 + 256;

  // CSR + static aggregates
  k_init<<<cdiv(NN * CEC, 256), 256, 0, stream>>>(ptr, pooled, counts, stats, ea32);
  k_scatter<<<NE / 32, 256, 0, stream>>>(eattr, ei, ea32);
  k_count<<<1250 + 40, 256, 0, stream>>>(ei, ptr, batch, counts);
  k_scan<<<1, 1024, 0, stream>>>(ptr, pos, degf);
  k_fill<<<1250, 256, 0, stream>>>(ei, pos, srcs);
  k_prep<<<1250, 256, 0, stream>>>((const float4*)x, degf, A1, xb);
  k_eag<<<NN / 4, 256, 0, stream>>>(ea32, xb, ptr, srcs, A1, A23);
  k_wt3<<<1472, 256, 0, stream>>>(W1, W2, W3, Wt1, Wt2, Wt3);

  dim3 ggrid(cdiv(NN, 64), CHID / 64);

  // layer 1
  k_gemm<<<ggrid, 256, 0, stream>>>(A1, Wt1, b1, degf, tmp, cs1, cq1, K1);
  k_bnapply<<<cdiv(NN * 64, 256), 256, 0, stream>>>((const float4*)tmp, cs1, cq1, g1, be1, A23, hb, degf);

  // layer 2
  k_gather256<<<NN / 2, 256, 0, stream>>>(hb, ptr, srcs, A23);
  k_gemm<<<ggrid, 256, 0, stream>>>(A23, Wt2, b2, degf, tmp, cs2, cq2, K23);
  k_bnapply<<<cdiv(NN * 64, 256), 256, 0, stream>>>((const float4*)tmp, cs2, cq2, g2, be2, A23, hb, degf);

  // layer 3
  k_gather256<<<NN / 2, 256, 0, stream>>>(hb, ptr, srcs, A23);
  k_gemm<<<ggrid, 256, 0, stream>>>(A23, Wt3, b3, degf, tmp, cs3, cq3, K23);
  k_poolbn<<<cdiv(NN, 64), 256, 0, stream>>>(tmp, cs3, cq3, g3, be3, batch, pooled);

  // MLP head
  k_fc1<<<NB * 4, 128, 0, stream>>>(pooled, counts, nbr, fc1w, fc1b, zmlp);
  k_fc2<<<NB, 64, 0, stream>>>(zmlp, fc2w, fc2b, out);
}